// Round 10
// baseline (288.002 us; speedup 1.0000x reference)
//
#include <hip/hip_runtime.h>

__device__ __forceinline__ float silu_f(float x) { return x / (1.f + __expf(-x)); }

// ---------------- A-operand descriptor ----------------
struct AOp {
  const float* P;    // matrix (or t-vector for tgen)
  const float* w1;   // tgen weight row
  const float* b0;   // tgen bias
  int lda;
  int tgen;          // A[m][k] = silu(P[m]*w1[k] + b0[k])
};

// ---------------- multi-problem split-K partial GEMM, 64x64 tile, 4x4/thread, LDS dbuf ----
// grid.z = NPROB << ls ; zi = z>>ls selects problem, s = z & ((1<<ls)-1) = K-slab.
// Raw partials to O[zi] + s*slabMN. A operands are compact (NS=1) or tgen.
template <int NPROB, int T1GEN>
__global__ __launch_bounds__(256) void gemm_p(
    AOp a0, AOp a1,
    const float* __restrict__ B0, const float* __restrict__ B1,
    const float* __restrict__ B2, int ldb,
    float* __restrict__ O0, float* __restrict__ O1, float* __restrict__ O2,
    int ldc, int Kslab, int ls, long slabMN) {
  __shared__ float As[2][32][68];
  __shared__ float Bs[2][32][68];
  const int tid = threadIdx.x;
  const int z = blockIdx.z;
  const int zi = (NPROB > 1) ? (z >> ls) : 0;
  const int s  = (NPROB > 1) ? (z & ((1 << ls) - 1)) : z;
  const AOp a = (NPROB > 1 && zi == 1) ? a1 : a0;
  const float* Bp = ((NPROB > 2 && zi == 2) ? B2 : (zi == 1) ? B1 : B0)
                    + (long)(s * Kslab) * ldb;
  float* Obase = ((NPROB > 2 && zi == 2) ? O2 : (zi == 1) ? O1 : O0)
                 + (long)s * slabMN;
  const int kbase = s * Kslab;
  const long bm = blockIdx.y * 64, bn = blockIdx.x * 64;
  const int tg = T1GEN ? a.tgen : 0;

  float acc[4][4] = {};
  const int ar = tid >> 3;        // 0..31
  const int ak = (tid & 7) << 2;  // 0..28
  const int br = tid >> 4;        // 0..15
  const int bn4 = (tid & 15) << 2;
  const int ty = tid >> 4, tx = tid & 15;

  float4 rA[2];
  float4 rB[2];
  float4 rW, rC;
  float tm0 = 0.f, tm1 = 0.f;

  auto loadA = [&](int k0) {
    int kg = kbase + k0 + ak;
    if (T1GEN && tg) {
      rW = *(const float4*)&a.w1[kg];
      rC = *(const float4*)&a.b0[kg];
    } else {
#pragma unroll
      for (int h = 0; h < 2; ++h)
        rA[h] = *(const float4*)&a.P[(bm + ar + h * 32) * (long)a.lda + kg];
    }
  };
  auto loadB = [&](int k0) {
#pragma unroll
    for (int h = 0; h < 2; ++h)
      rB[h] = *(const float4*)&Bp[(long)(k0 + br + h * 16) * ldb + bn + bn4];
  };
  auto store = [&](int buf) {
#pragma unroll
    for (int h = 0; h < 2; ++h) {
      int m = ar + h * 32;
      float4 av;
      if (T1GEN && tg) {
        float tm = h ? tm1 : tm0;
        av.x = silu_f(tm * rW.x + rC.x);
        av.y = silu_f(tm * rW.y + rC.y);
        av.z = silu_f(tm * rW.z + rC.z);
        av.w = silu_f(tm * rW.w + rC.w);
      } else {
        av = rA[h];
      }
      As[buf][ak + 0][m] = av.x; As[buf][ak + 1][m] = av.y;
      As[buf][ak + 2][m] = av.z; As[buf][ak + 3][m] = av.w;
    }
#pragma unroll
    for (int h = 0; h < 2; ++h) *(float4*)&Bs[buf][br + h * 16][bn4] = rB[h];
  };

  if (T1GEN && tg) { tm0 = a.P[bm + ar]; tm1 = a.P[bm + ar + 32]; }
  loadA(0); loadB(0);
  store(0);
  if (32 < Kslab) { loadA(32); loadB(32); }

  int cur = 0;
  for (int k0 = 0; k0 < Kslab; k0 += 32) {
    __syncthreads();
    if (k0 + 32 < Kslab) store(cur ^ 1);
    if (k0 + 64 < Kslab) { loadA(k0 + 64); loadB(k0 + 64); }
#pragma unroll
    for (int k = 0; k < 32; ++k) {
      float4 a4 = *(const float4*)&As[cur][k][ty << 2];
      float4 b4 = *(const float4*)&Bs[cur][k][tx << 2];
      float am[4] = {a4.x, a4.y, a4.z, a4.w};
      float bv[4] = {b4.x, b4.y, b4.z, b4.w};
#pragma unroll
      for (int i = 0; i < 4; ++i)
#pragma unroll
        for (int j = 0; j < 4; ++j) acc[i][j] = fmaf(am[i], bv[j], acc[i][j]);
    }
    cur ^= 1;
  }

  float* O = Obase + (bm + ty * 4) * (long)ldc + bn + tx * 4;
#pragma unroll
  for (int i = 0; i < 4; ++i) {
    float4 v = {acc[i][0], acc[i][1], acc[i][2], acc[i][3]};
    *(float4*)&O[(long)i * ldc] = v;
  }
}

// ---------------- BT full-GEMM (M only): C[z] = alpha * A[z] @ B[z]^T ----------------
__global__ __launch_bounds__(256) void gemm_bt(
    const float* __restrict__ A, int lda, const float* __restrict__ B, int ldb,
    float* __restrict__ OUT, int ldc, int K, float alpha,
    int zAoff, int zBoff, int zCoff) {
  __shared__ float As[2][32][68];
  __shared__ float Bs[2][32][68];
  const int tid = threadIdx.x;
  const int z = blockIdx.z;
  const long bm = blockIdx.y * 64, bn = blockIdx.x * 64;
  const float* Ab = A + (long)z * zAoff;
  const float* Bp = B + (long)z * zBoff;
  float* Obase = OUT + (long)z * zCoff;
  float acc[4][4] = {};
  const int ar = tid >> 3;
  const int ak = (tid & 7) << 2;
  const int ty = tid >> 4, tx = tid & 15;
  float4 rA[2], rB[2];
  auto loadAB = [&](int k0) {
#pragma unroll
    for (int h = 0; h < 2; ++h) {
      rA[h] = *(const float4*)&Ab[(bm + ar + h * 32) * (long)lda + k0 + ak];
      rB[h] = *(const float4*)&Bp[(bn + ar + h * 32) * (long)ldb + k0 + ak];
    }
  };
  auto store = [&](int buf) {
#pragma unroll
    for (int h = 0; h < 2; ++h) {
      int m = ar + h * 32;
      As[buf][ak + 0][m] = rA[h].x; As[buf][ak + 1][m] = rA[h].y;
      As[buf][ak + 2][m] = rA[h].z; As[buf][ak + 3][m] = rA[h].w;
      Bs[buf][ak + 0][m] = rB[h].x; Bs[buf][ak + 1][m] = rB[h].y;
      Bs[buf][ak + 2][m] = rB[h].z; Bs[buf][ak + 3][m] = rB[h].w;
    }
  };
  loadAB(0); store(0);
  if (32 < K) loadAB(32);
  int cur = 0;
  for (int k0 = 0; k0 < K; k0 += 32) {
    __syncthreads();
    if (k0 + 32 < K) store(cur ^ 1);
    if (k0 + 64 < K) loadAB(k0 + 64);
#pragma unroll
    for (int k = 0; k < 32; ++k) {
      float4 a4 = *(const float4*)&As[cur][k][ty << 2];
      float4 b4 = *(const float4*)&Bs[cur][k][tx << 2];
      float am[4] = {a4.x, a4.y, a4.z, a4.w};
      float bv[4] = {b4.x, b4.y, b4.z, b4.w};
#pragma unroll
      for (int i = 0; i < 4; ++i)
#pragma unroll
        for (int j = 0; j < 4; ++j) acc[i][j] = fmaf(am[i], bv[j], acc[i][j]);
    }
    cur ^= 1;
  }
  float* O = Obase + (bm + ty * 4) * (long)ldc + bn + tx * 4;
#pragma unroll
  for (int i = 0; i < 4; ++i) {
    float4 v = {alpha * acc[i][0], alpha * acc[i][1], alpha * acc[i][2],
                alpha * acc[i][3]};
    *(float4*)&O[(long)i * ldc] = v;
  }
}

// ---------------- slab-sum + bias + act -> compact (HBM/L3-BW bound) ----------------
template <int NS, int ACT>
__global__ __launch_bounds__(256) void sumk(
    const float* __restrict__ P, long slabMN,
    const float* __restrict__ b0, const float* __restrict__ b1, int bsplit,
    int cmask, float* __restrict__ out) {
  int i4 = (blockIdx.x * 256 + threadIdx.x) << 2;
  float4 s = *(const float4*)&P[i4];
#pragma unroll
  for (int si = 1; si < NS; ++si) {
    float4 p = *(const float4*)&P[(long)si * slabMN + i4];
    s.x += p.x; s.y += p.y; s.z += p.z; s.w += p.w;
  }
  int c = i4 & cmask;
  const float* bp = (b1 && c >= bsplit) ? (b1 + c - bsplit) : (b0 + c);
  float4 bb = *(const float4*)bp;
  s.x += bb.x; s.y += bb.y; s.z += bb.z; s.w += bb.w;
  if (ACT == 1) {
    s.x = silu_f(s.x); s.y = silu_f(s.y); s.z = silu_f(s.z); s.w = silu_f(s.w);
  }
  *(float4*)&out[i4] = s;
}

// reduce split-K partials: C = tanh(sum_s P[s] + bias)  (final stage, 16 slabs)
__global__ __launch_bounds__(256) void reduce_tanh(
    const float* __restrict__ P, int slabMN, int nslab,
    const float* __restrict__ bias, float* __restrict__ C) {
  int i4 = (blockIdx.x * 256 + threadIdx.x) << 2;
  float4 s = *(const float4*)&P[i4];
  for (int si = 1; si < nslab; ++si) {
    float4 p = *(const float4*)&P[(long)si * slabMN + i4];
    s.x += p.x; s.y += p.y; s.z += p.z; s.w += p.w;
  }
  int c = i4 & 127;
  float4 v = {tanhf(s.x + bias[c]), tanhf(s.y + bias[c + 1]),
              tanhf(s.z + bias[c + 2]), tanhf(s.w + bias[c + 3])};
  *(float4*)&C[i4] = v;
}

// ---------------- fused sparse attention + pooling (frozen from round 9) ----------------
__global__ __launch_bounds__(256) void attn_kernel(
    const float* __restrict__ PBq,  // qb slabs @0..3*262144; vb slabs @4*262144..
    const float* __restrict__ bq,
    const float* __restrict__ bv,
    const float* __restrict__ kf,   // raw [128][512]
    const float* __restrict__ Mm,   // [128][1024] (alpha 0.00125 applied)
    const float* __restrict__ vf,   // raw [128][512]
    float* __restrict__ pool) {
  const int b = blockIdx.x, h = blockIdx.y;
  const int tid = threadIdx.x;
  __shared__ float uq[64];
  __shared__ float uls[128];
  __shared__ float wpart[4][128];
  __shared__ float wcol[128];
  __shared__ float ppart[2][64];

  if (tid < 64) {
    int c = h * 64 + tid;
    long o = (long)b * 512 + c;
    uq[tid] = PBq[o] + PBq[262144 + o] + PBq[524288 + o] + PBq[786432 + o] + bq[c];
  }
  __syncthreads();
  if (tid < 128) {
    const float* kr = kf + (long)tid * 512 + h * 64;
    float acc = 0.f;
#pragma unroll
    for (int d4 = 0; d4 < 16; ++d4) {
      float4 kv = *(const float4*)&kr[d4 * 4];
      acc += uq[d4 * 4] * kv.x + uq[d4 * 4 + 1] * kv.y +
             uq[d4 * 4 + 2] * kv.z + uq[d4 * 4 + 3] * kv.w;
    }
    uls[tid] = 0.0125f * acc;
  }
  __syncthreads();

  const int lane = tid & 63;
  const int wave = tid >> 6;
  const float u0 = uls[lane], u1 = uls[lane + 64];

  float blo = -0.5f, bhi = 0.5f;
#pragma unroll
  for (int it = 0; it < 11; ++it) {
    float mid = 0.5f * (blo + bhi);
    int n = __popcll(__ballot(u0 >= mid)) + __popcll(__ballot(u1 >= mid));
    bool ge = (n >= 64);
    blo = ge ? mid : blo;
    bhi = ge ? bhi : mid;
  }
  const float wlo = blo - 0.014f, whi = blo + 0.014f;

  float wc0 = 0.f, wc1 = 0.f;
  const float* Mh = Mm + h * 128;
  const int i0 = wave * 32;
  float a0r = Mh[(long)i0 * 1024 + lane];
  float a1r = Mh[(long)i0 * 1024 + lane + 64];
  float b0r = Mh[(long)(i0 + 1) * 1024 + lane];
  float b1r = Mh[(long)(i0 + 1) * 1024 + lane + 64];
  for (int r = 0; r < 32; r += 2) {
    float TA0 = u0 + a0r, TA1 = u1 + a1r;
    float TB0 = u0 + b0r, TB1 = u1 + b1r;
    if (r < 30) {
      a0r = Mh[(long)(i0 + r + 2) * 1024 + lane];
      a1r = Mh[(long)(i0 + r + 2) * 1024 + lane + 64];
      b0r = Mh[(long)(i0 + r + 3) * 1024 + lane];
      b1r = Mh[(long)(i0 + r + 3) * 1024 + lane + 64];
    }
    float loA = wlo, hiA = whi, loB = wlo, hiB = whi;
#pragma unroll
    for (int it = 0; it < 5; ++it) {
      float midA = 0.5f * (loA + hiA), midB = 0.5f * (loB + hiB);
      int nA = __popcll(__ballot(TA0 >= midA)) + __popcll(__ballot(TA1 >= midA));
      int nB = __popcll(__ballot(TB0 >= midB)) + __popcll(__ballot(TB1 >= midB));
      bool gA = (nA >= 64), gB = (nB >= 64);
      loA = gA ? midA : loA; hiA = gA ? hiA : midA;
      loB = gB ? midB : loB; hiB = gB ? hiB : midB;
    }
    float pA0 = (TA0 >= loA) ? __expf(TA0 - loA) : 0.f;
    float pA1 = (TA1 >= loA) ? __expf(TA1 - loA) : 0.f;
    float pB0 = (TB0 >= loB) ? __expf(TB0 - loB) : 0.f;
    float pB1 = (TB1 >= loB) ? __expf(TB1 - loB) : 0.f;
    float sA = pA0 + pA1, sB = pB0 + pB1;
#pragma unroll
    for (int d = 1; d < 64; d <<= 1) {
      sA += __shfl_xor(sA, d);
      sB += __shfl_xor(sB, d);
    }
    float ivA = 1.f / sA, ivB = 1.f / sB;
    wc0 += pA0 * ivA + pB0 * ivB;
    wc1 += pA1 * ivA + pB1 * ivB;
  }
  wpart[wave][lane] = wc0;
  wpart[wave][lane + 64] = wc1;
  __syncthreads();
  if (tid < 128) {
    wcol[tid] = (wpart[0][tid] + wpart[1][tid] + wpart[2][tid] + wpart[3][tid]) *
                (1.f / 128.f);
  }
  __syncthreads();
  if (wave < 2) {
    int j0 = wave * 64;
    const float* vfp = vf + h * 64 + lane;
    float acc = 0.f;
#pragma unroll 8
    for (int jj = 0; jj < 64; ++jj) acc += wcol[j0 + jj] * vfp[(long)(j0 + jj) * 512];
    ppart[wave][lane] = acc;
  }
  __syncthreads();
  if (tid < 64) {
    int d = tid;
    int c = h * 64 + d;
    long o = (long)b * 512 + c;
    long vb0 = 4 * 262144;
    float v = PBq[vb0 + o] + PBq[vb0 + 262144 + o] + PBq[vb0 + 524288 + o] +
              PBq[vb0 + 786432 + o] + bv[c];
    pool[o] = 0.1f * (ppart[0][d] + ppart[1][d]) + v;
  }
}

// LayerNorm over 512 cols (input = NSLAB partial slabs + bias), eps 1e-5, affine
template <int NSLAB>
__global__ __launch_bounds__(256) void ln_kernel(const float* __restrict__ P,
                                                 const float* __restrict__ bias,
                                                 const float* __restrict__ g,
                                                 const float* __restrict__ bb,
                                                 float* __restrict__ Y) {
  int row = blockIdx.x;
  int tid = threadIdx.x;
  long o0 = (long)row * 512 + tid;
  long o1 = o0 + 256;
  float v0 = bias[tid], v1 = bias[tid + 256];
#pragma unroll
  for (int s = 0; s < NSLAB; ++s) {
    v0 += P[(long)s * 262144 + o0];
    v1 += P[(long)s * 262144 + o1];
  }
  float s = v0 + v1;
#pragma unroll
  for (int d = 1; d < 64; d <<= 1) s += __shfl_xor(s, d);
  __shared__ float r1[4], r2[4];
  if ((tid & 63) == 0) r1[tid >> 6] = s;
  __syncthreads();
  float mean = (r1[0] + r1[1] + r1[2] + r1[3]) * (1.f / 512.f);
  float d0 = v0 - mean, d1 = v1 - mean;
  float q = d0 * d0 + d1 * d1;
#pragma unroll
  for (int d = 1; d < 64; d <<= 1) q += __shfl_xor(q, d);
  if ((tid & 63) == 0) r2[tid >> 6] = q;
  __syncthreads();
  float var = (r2[0] + r2[1] + r2[2] + r2[3]) * (1.f / 512.f);
  float inv = rsqrtf(var + 1e-5f);
  Y[(long)row * 512 + tid] = d0 * inv * g[tid] + bb[tid];
  Y[(long)row * 512 + tid + 256] = d1 * inv * g[tid + 256] + bb[tid + 256];
}

// ---------------- host ----------------

extern "C" void kernel_launch(void* const* d_in, const int* in_sizes, int n_in,
                              void* d_out, int out_size, void* d_ws, size_t ws_size,
                              hipStream_t stream) {
  const float* x_t = (const float*)d_in[0];
  const float* t_in = (const float*)d_in[1];
  const float* te_w1 = (const float*)d_in[2];
  const float* te_b1 = (const float*)d_in[3];
  const float* te_w2 = (const float*)d_in[4];
  const float* te_b2 = (const float*)d_in[5];
  const float* fe_w1 = (const float*)d_in[6];
  const float* fe_b1 = (const float*)d_in[7];
  const float* fe_w2 = (const float*)d_in[8];
  const float* fe_b2 = (const float*)d_in[9];
  const float* fp_w1 = (const float*)d_in[10];
  const float* fp_b1 = (const float*)d_in[11];
  const float* fp_w2 = (const float*)d_in[12];
  const float* fp_b2 = (const float*)d_in[13];
  const float* fp_w3 = (const float*)d_in[14];
  const float* fp_b3 = (const float*)d_in[15];
  const float* fid = (const float*)d_in[16];
  const float* wq = (const float*)d_in[17];
  const float* bq = (const float*)d_in[18];
  const float* wk = (const float*)d_in[19];
  // d_in[20]=bk cancels (row-constant in softmax) -> unused
  const float* wv = (const float*)d_in[21];
  const float* bv = (const float*)d_in[22];
  const float* wo = (const float*)d_in[23];
  const float* bo = (const float*)d_in[24];
  const float* gp_w1 = (const float*)d_in[25];
  const float* gp_b1 = (const float*)d_in[26];
  const float* gp_w2 = (const float*)d_in[27];
  const float* gp_b2 = (const float*)d_in[28];
  const float* ln_g = (const float*)d_in[29];
  const float* ln_b = (const float*)d_in[30];
  const float* dn_w1 = (const float*)d_in[31];
  const float* dn_b1 = (const float*)d_in[32];
  const float* dn_w2 = (const float*)d_in[33];
  const float* dn_b2 = (const float*)d_in[34];
  const float* dn_w3 = (const float*)d_in[35];
  const float* dn_b3 = (const float*)d_in[36];

  // Unified layout (floats) — 3,473,408 = 13.25 MiB (< proven 17.25 MiB):
  // single partial arena P (2M = 8x512^2 slabs or 4x512x1024 or 16x512x128),
  // compacts decouple producer/consumer so no ping-pong needed.
  float* W = (float*)d_ws;
  float* P  = W;                   // 2,097,152
  float* XC = W + 2097152;         // 524,288 compact [512][1024]
  float* SA = W + 2621440;         // 262,144 compact [512][512]
  float* SB = W + 2883584;         // 262,144 compact [512][512]
  float* qf = W + 3145728;         // 65,536
  float* kf = W + 3211264;         // 65,536
  float* vf = W + 3276800;         // 65,536
  float* Mb = W + 3342336;         // 131,072

  auto ap = [](const float* Pm, int lda) {
    AOp a; a.P = Pm; a.w1 = nullptr; a.b0 = nullptr; a.lda = lda; a.tgen = 0;
    return a;
  };

  // ---- qf/kf/vf (raw; scales live in M-alpha and attn) ----
  gemm_p<3, 0><<<dim3(8, 2, 3), 256, 0, stream>>>(
      ap(fid, 128), ap(fid, 128), wq, wk, wv, 512, qf, kf, vf, 512, 128, 0, 0);
  // M[h] = 0.00125 * qf_h @ kf_h^T
  gemm_bt<<<dim3(2, 2, 8), 256, 0, stream>>>(qf, 512, kf, 512, Mb, 1024, 64,
                                             0.00125f, 64, 64, 128);
  // ---- act1: x_t @ fe_w1 (K=128), s4 -> P ----
  gemm_p<1, 0><<<dim3(8, 8, 4), 256, 0, stream>>>(
      ap(x_t, 128), ap(x_t, 128), fe_w1, nullptr, nullptr, 512,
      P, nullptr, nullptr, 512, 32, 0, 262144);
  sumk<4, 1><<<256, 256, 0, stream>>>(P, 262144, fe_b1, nullptr, 0, 511, SA);
  // ---- xcat: {SA @ fe_w2, tgen @ te_w2}, s4 each (512 blocks) -> P ----
  {
    AOp a1; a1.P = t_in; a1.w1 = te_w1; a1.b0 = te_b1; a1.lda = 0; a1.tgen = 1;
    gemm_p<2, 1><<<dim3(8, 8, 8), 256, 0, stream>>>(
        ap(SA, 512), a1, fe_w2, te_w2, nullptr, 512,
        P, P + 512, nullptr, 1024, 128, 2, 524288);
  }
  sumk<4, 0><<<512, 256, 0, stream>>>(P, 524288, fe_b2, te_b2, 512, 1023, XC);
  // ---- h1: XC @ fp_w1 (K=1024), s8 (512 blocks) -> P ----
  gemm_p<1, 0><<<dim3(8, 8, 8), 256, 0, stream>>>(
      ap(XC, 1024), ap(XC, 1024), fp_w1, nullptr, nullptr, 512,
      P, nullptr, nullptr, 512, 128, 0, 262144);
  sumk<8, 1><<<256, 256, 0, stream>>>(P, 262144, fp_b1, nullptr, 0, 511, SB);
  // ---- h2: SB @ fp_w2, s8 -> P ----
  gemm_p<1, 0><<<dim3(8, 8, 8), 256, 0, stream>>>(
      ap(SB, 512), ap(SB, 512), fp_w2, nullptr, nullptr, 512,
      P, nullptr, nullptr, 512, 64, 0, 262144);
  sumk<8, 1><<<256, 256, 0, stream>>>(P, 262144, fp_b2, nullptr, 0, 511, SA);
  // ---- base: SA @ fp_w3, s8 -> P ----
  gemm_p<1, 0><<<dim3(8, 8, 8), 256, 0, stream>>>(
      ap(SA, 512), ap(SA, 512), fp_w3, nullptr, nullptr, 512,
      P, nullptr, nullptr, 512, 64, 0, 262144);
  sumk<8, 0><<<256, 256, 0, stream>>>(P, 262144, fp_b3, nullptr, 0, 511, SB);
  // ---- qb & vb: SB @ {wq, wv}, s4 each (512 blocks) -> P (8 slabs) ----
  gemm_p<2, 0><<<dim3(8, 8, 8), 256, 0, stream>>>(
      ap(SB, 512), ap(SB, 512), wq, wv, nullptr, 512,
      P, P + 1048576, nullptr, 512, 128, 2, 262144);
  // ---- fused attention -> pool (SA) ----
  attn_kernel<<<dim3(512, 8), 256, 0, stream>>>(P, bq, bv, kf, Mb, vf, SA);
  // ---- g1: SA @ wo, s8 -> P ----
  gemm_p<1, 0><<<dim3(8, 8, 8), 256, 0, stream>>>(
      ap(SA, 512), ap(SA, 512), wo, nullptr, nullptr, 512,
      P, nullptr, nullptr, 512, 64, 0, 262144);
  sumk<8, 0><<<256, 256, 0, stream>>>(P, 262144, bo, nullptr, 0, 511, SB);
  // ---- g2: SB @ gp_w1 [512x1024], s4 (512 blocks) -> P ----
  gemm_p<1, 0><<<dim3(16, 8, 4), 256, 0, stream>>>(
      ap(SB, 512), ap(SB, 512), gp_w1, nullptr, nullptr, 1024,
      P, nullptr, nullptr, 1024, 128, 0, 524288);
  sumk<4, 1><<<512, 256, 0, stream>>>(P, 524288, gp_b1, nullptr, 0, 1023, XC);
  // ---- g3: XC @ gp_w2 (K=1024), s8 -> P ----
  gemm_p<1, 0><<<dim3(8, 8, 8), 256, 0, stream>>>(
      ap(XC, 1024), ap(XC, 1024), gp_w2, nullptr, nullptr, 512,
      P, nullptr, nullptr, 512, 128, 0, 262144);
  // gn = LN(sum8 + gp_b2) -> SA
  ln_kernel<8><<<512, 256, 0, stream>>>(P, gp_b2, ln_g, ln_b, SA);
  // ---- r1: SA @ dn_w1 [512x1024], s4 (512 blocks) -> P ----
  gemm_p<1, 0><<<dim3(16, 8, 4), 256, 0, stream>>>(
      ap(SA, 512), ap(SA, 512), dn_w1, nullptr, nullptr, 1024,
      P, nullptr, nullptr, 1024, 128, 0, 524288);
  sumk<4, 1><<<512, 256, 0, stream>>>(P, 524288, dn_b1, nullptr, 0, 1023, XC);
  // ---- r2: XC @ dn_w2 [1024x1024], s4 (512 blocks, Kslab 256) -> P ----
  gemm_p<1, 0><<<dim3(16, 8, 4), 256, 0, stream>>>(
      ap(XC, 1024), ap(XC, 1024), dn_w2, nullptr, nullptr, 1024,
      P, nullptr, nullptr, 1024, 256, 0, 524288);
  sumk<4, 1><<<512, 256, 0, stream>>>(P, 524288, dn_b2, nullptr, 0, 1023, XC);
  // ---- out: XC @ dn_w3[:, :128], s16 (256 blocks, Kslab 64) -> P ----
  gemm_p<1, 0><<<dim3(2, 8, 16), 256, 0, stream>>>(
      ap(XC, 1024), ap(XC, 1024), dn_w3, nullptr, nullptr, 256,
      P, nullptr, nullptr, 128, 64, 0, 65536);
  // sum16 + dn_b3 -> tanh -> d_out (f32)
  reduce_tanh<<<64, 256, 0, stream>>>(P, 65536, 16, dn_b3, (float*)d_out);
}